// Round 15
// baseline (332.174 us; speedup 1.0000x reference)
//
#include <hip/hip_runtime.h>

// ---------------- constants ----------------
#define BATCH 8
#define NN    128
#define DD    128
#define MM    16
#define DEPTH 4
#define EIN   257      // 2*D+1
#define H1    514      // 2*EIN
#define KPAD  544      // H1 padded to 17 chunks of 32
#define NCH   17
#define NODES (BATCH*NN)   // 1024
#define BQ_B  69632        // per-batch Bq floats: 17*4096

typedef __attribute__((ext_vector_type(8))) short short8;   // 8 bf16
typedef __attribute__((ext_vector_type(4))) float floatx4;  // MFMA C/D

__device__ __forceinline__ float b2f(unsigned short u) {
    return __uint_as_float(((unsigned int)u) << 16);
}
__device__ __forceinline__ unsigned short f2b(float f) {
    unsigned int x = __float_as_uint(f);
    unsigned int r = (x + 0x7fffu + ((x >> 16) & 1u)) >> 16;
    return (unsigned short)r;
}
// scalar silu (epilogue): v_exp_f32 + v_rcp_f32
__device__ __forceinline__ float siluf(float x) {
    float t = __builtin_amdgcn_exp2f(x * -1.442695040888963f);
    return x * __builtin_amdgcn_rcpf(1.0f + t);
}
__device__ __forceinline__ float loadf(const void* p, size_t idx, int isbf) {
    return isbf ? b2f(((const unsigned short*)p)[idx]) : ((const float*)p)[idx];
}
// 2xf32 -> packed bf16 (round-half-up via +0x8000 then byte-perm)
__device__ __forceinline__ unsigned int pk2(float x, float y) {
    unsigned int xb = __float_as_uint(x) + 0x8000u;
    unsigned int yb = __float_as_uint(y) + 0x8000u;
    return __builtin_amdgcn_perm(yb, xb, 0x07060302);
}
// 4 silus sharing ONE v_rcp: r = rcp(prod(1+u_i)); recover each 1/(1+u_i)
// via prefix products. exp input clamped at -16 so prod <= e^64 ... actually
// u_i <= e^16 => prod <= e^64 overflows; clamp keeps u <= 8.9e6, prod <= 6e27
// < 3.4e38. silu(-16) ~ -1.8e-6 ~ 0, so clamp is numerically free.
__device__ __forceinline__ void silu4pk(float x0, float x1, float x2, float x3,
                                        unsigned int* lo, unsigned int* hi) {
    const float nl2e = -1.442695040888963f;
    float u0 = __builtin_amdgcn_exp2f(fmaxf(x0, -16.f) * nl2e);
    float u1 = __builtin_amdgcn_exp2f(fmaxf(x1, -16.f) * nl2e);
    float u2 = __builtin_amdgcn_exp2f(fmaxf(x2, -16.f) * nl2e);
    float u3 = __builtin_amdgcn_exp2f(fmaxf(x3, -16.f) * nl2e);
    float a0 = 1.f + u0, a1 = 1.f + u1, a2 = 1.f + u2, a3 = 1.f + u3;
    float d01 = a0 * a1, d23 = a2 * a3;
    float r = __builtin_amdgcn_rcpf(d01 * d23);
    float r01 = r * d23, r23 = r * d01;       // 1/d01, 1/d23
    float h0 = x0 * (r01 * a1), h1 = x1 * (r01 * a0);
    float h2 = x2 * (r23 * a3), h3 = x3 * (r23 * a2);
    *lo = pk2(h0, h1); *hi = pk2(h2, h3);
}

// ---------------- workspace layout (floats) ----------------
#define OFF_FEATS   0
#define OFF_COORSA  131072
#define OFF_COORSB  134144
#define OFF_AB      137216      // Ab [1024][544]
// Bq LANE-LINEAR layout: [8 b][17 kc][8 jt][2 hsel][64 lane][4 t]
#define OFF_BQ      694272
#define OFF_CPK     1267712     // [4][1216]
#define OFF_WLB     1272576     // [4][560]
#define OFF_W2F     1274816     // [4][17][64] int4
#define OFF_FLAG    1292224
#define OFF_FB16    1292228     // u16[1024][128] = 65536 float slots
#define OFF_W1F     1357764     // int4[4][68][4][64] = 278528 float slots

// ---------------- k_init: detect + node init + W2/W1 frags + cpk -----------
__global__ __launch_bounds__(256) void k_init(
    const int* __restrict__ z, const void* __restrict__ pos,
    const void* __restrict__ emb,
    const void* __restrict__ e_w1, const void* __restrict__ e_w2,
    const void* __restrict__ e_b2,
    const void* __restrict__ c_w1, const void* __restrict__ c_b1,
    const void* __restrict__ c_w2, const void* __restrict__ c_b2,
    float* __restrict__ feats, unsigned short* __restrict__ fb16,
    float* __restrict__ coorsA,
    float* __restrict__ wlb, int4* __restrict__ w2frag,
    int4* __restrict__ w1frag,
    float* __restrict__ cpack, int* __restrict__ flag) {
    __shared__ int sfl;
    int tid = threadIdx.x, bx = blockIdx.x;
    if (tid < 64) {
        float f = fabsf(__uint_as_float(((const unsigned int*)pos)[tid]));
        bool ok = (f == 0.f) || (f > 1e-8f && f < 1e8f);
        unsigned long long v = __ballot(ok);
        if (tid == 0) sfl = (__builtin_popcountll(v) >= 32) ? 0 : 1;
    }
    __syncthreads();
    int isbf = sfl;
    if (bx == 0 && tid == 0) *flag = isbf;
    if (bx < 512) {
        int node = 2 * bx + (tid >> 7), t = tid & 127;
        int zi = z[node];
        float v = loadf(emb, (size_t)zi * DD + t, isbf);
        feats[node * DD + t] = v;
        fb16[node * DD + t] = f2b(v);
        if (t < 3) coorsA[node * 3 + t] = loadf(pos, node * 3 + t, isbf);
    } else if (bx < 580) {
        int p = bx - 512;
        int layer = p / NCH, kc = p % NCH;
        if (tid < 64) {
            int quad = tid >> 4, c = tid & 15;
            size_t w2base = (size_t)layer * H1 * MM;
            unsigned int u[4];
            #pragma unroll
            for (int pp = 0; pp < 4; ++pp) {
                int k0 = kc * 32 + quad * 8 + 2 * pp, k1 = k0 + 1;
                float f0 = (k0 < H1) ? loadf(e_w2, w2base + (size_t)k0 * MM + c, isbf) : 0.f;
                float f1 = (k1 < H1) ? loadf(e_w2, w2base + (size_t)k1 * MM + c, isbf) : 0.f;
                u[pp] = pk2(f0, f1);
            }
            w2frag[(layer * NCH + kc) * 64 + tid] =
                make_int4((int)u[0], (int)u[1], (int)u[2], (int)u[3]);
            if (kc == 0) {
                size_t wlbase = ((size_t)layer * EIN + 256) * H1;
                for (int t = tid; t < KPAD; t += 64)
                    wlb[layer * 560 + t] = (t < H1) ? loadf(e_w1, wlbase + t, isbf) : 0.f;
                if (tid < 16)
                    wlb[layer * 560 + 544 + tid] = loadf(e_b2, layer * MM + tid, isbf);
            }
        }
    } else if (bx < 584) {
        int l = bx - 580;
        for (int idx = tid; idx < 1024; idx += 256) {
            int c = idx >> 6, hh = idx & 63;
            cpack[l * 1216 + hh * 16 + c] = loadf(c_w1, l * 1024 + c * 64 + hh, isbf);
        }
        if (tid < 64)        cpack[l * 1216 + 1024 + tid] = loadf(c_b1, l * 64 + tid, isbf);
        else if (tid < 128)  cpack[l * 1216 + 1088 + tid - 64] = loadf(c_w2, l * 64 + tid - 64, isbf);
        else if (tid == 128) cpack[l * 1216 + 1152] = loadf(c_b2, l, isbf);
    } else {
        // W1 B-fragments for the k1 MFMA GEMM: n-tile layout [A544|B544]
        int p = bx - 584;
        int l = p / 68, nt = p % 68;
        int kcd = tid >> 6, lane = tid & 63;
        int quad = lane >> 4, c16 = lane & 15;
        int n_local = nt * 16 + c16;
        int half = n_local >= KPAD;
        int k_out = n_local - (half ? KPAD : 0);
        size_t wbase = (size_t)l * EIN * H1 + (size_t)(half ? 128 : 0) * H1 + k_out;
        unsigned int u[4];
        #pragma unroll
        for (int pp = 0; pp < 4; ++pp) {
            int d0 = kcd * 32 + quad * 8 + 2 * pp;
            float f0 = (k_out < H1) ? loadf(e_w1, wbase + (size_t)d0 * H1, isbf) : 0.f;
            float f1 = (k_out < H1) ? loadf(e_w1, wbase + (size_t)(d0 + 1) * H1, isbf) : 0.f;
            u[pp] = pk2(f0, f1);
        }
        w1frag[((size_t)(l * 68 + nt) * 4 + kcd) * 64 + lane] =
            make_int4((int)u[0], (int)u[1], (int)u[2], (int)u[3]);
    }
}

// ---------------- K1: MFMA GEMM, 4 M-tiles/block (w1frag reused 4x) --------
// grid 272: bx = mg(16) x ng(17); wave w owns ntile = ng*4+w across 4 mtiles.
__global__ __launch_bounds__(256) void k1_ab(
    const unsigned short* __restrict__ fb16, const int4* __restrict__ w1f,
    const void* __restrict__ b1raw, unsigned int b1off,
    float* __restrict__ Ab, float* __restrict__ Bq,
    const int* __restrict__ flagp) {
    int bx = blockIdx.x;
    int mg = bx & 15, ng = bx >> 4;
    int tid = threadIdx.x, w = tid >> 6, lane = tid & 63;
    int quad = lane >> 4, c16 = lane & 15;
    int isbf = *flagp;
    int ntile = ng * 4 + w;
    int n_local = ntile * 16 + c16;
    int half = n_local >= KPAD;
    int k_out = n_local - (half ? KPAD : 0);

    const int4* bp = w1f + (size_t)ntile * 4 * 64 + lane;
    union { int4 i4; short8 s; } bf[4];
    #pragma unroll
    for (int kcd = 0; kcd < 4; ++kcd) bf[kcd].i4 = bp[kcd * 64];
    float bias = (!half && k_out < H1) ? loadf(b1raw, b1off + k_out, isbf) : 0.f;

    #pragma unroll
    for (int mi = 0; mi < 4; ++mi) {
        int mt = mg * 4 + mi;
        const unsigned short* ap = fb16 + (size_t)(mt * 16 + c16) * DD + quad * 8;
        floatx4 acc = {0.f, 0.f, 0.f, 0.f};
        #pragma unroll
        for (int kcd = 0; kcd < 4; ++kcd) {
            short8 af = *(const short8*)(ap + kcd * 32);
            acc = __builtin_amdgcn_mfma_f32_16x16x32_bf16(af, bf[kcd].s, acc, 0, 0, 0);
        }
        if (!half) {
            #pragma unroll
            for (int r = 0; r < 4; ++r)
                Ab[(size_t)(mt * 16 + quad * 4 + r) * KPAD + k_out] = acc[r] + bias;
        } else {
            int kc = k_out >> 5, kk = k_out & 31;
            int qd = kk >> 3, hsel = (kk >> 2) & 1, tt = k_out & 3;
            #pragma unroll
            for (int r = 0; r < 4; ++r) {
                int node = mt * 16 + quad * 4 + r;
                int bb = node >> 7, j = node & 127;
                int jt = j >> 4, lj = qd * 16 + (j & 15);
                Bq[(size_t)bb * BQ_B + kc * 4096 + jt * 512 + hsel * 256
                   + lj * 4 + tt] = acc[r];
            }
        }
    }
}

// ---------------- K2f: 2-node, 8-wave, k-split pair kernel + node update ---
__global__ __launch_bounds__(512, 4) void k2_pair(
    const float* __restrict__ Ab, const float* __restrict__ Bq,
    const float* __restrict__ coorsIn, float* __restrict__ coorsOut,
    float* __restrict__ feats, unsigned short* __restrict__ fb16,
    const float* __restrict__ wlbL,     // [560]: wl[544] + b2[16]
    const short8* __restrict__ w2fragL, // [17][64] bf16 frags
    const float* __restrict__ cpk,      // [1216]
    const void* __restrict__ gln, const void* __restrict__ bln,
    const void* __restrict__ w1r, const void* __restrict__ b1r,
    const void* __restrict__ w2r, const void* __restrict__ b2r,
    unsigned int layer, const int* __restrict__ flagp) {
    __shared__ float Ms[2][128 * 17];
    __shared__ float px[128], py[128], pz[128];
    __shared__ float msum[2][16][16];
    __shared__ float cwf[2][2][128];
    __shared__ float red[4][3];
    __shared__ float fr[2][128];
    __shared__ float ni[2][144];
    __shared__ float hid[2][256];
    __shared__ float part[2][2][128];
    int tid = threadIdx.x;
    int b = blockIdx.x & 7, ip = blockIdx.x >> 3;   // XCD-aware swizzle
    int i0 = ip * 2;
    int node0 = b * NN + i0;
    int w = tid >> 6, lane = tid & 63;
    int quad = lane >> 4, c16 = lane & 15;
    int kg = w >> 2, wj = w & 3;
    int isbf = *flagp;

    if (tid < 128) {
        int g = (b * NN + tid) * 3;
        px[tid] = coorsIn[g]; py[tid] = coorsIn[g + 1]; pz[tid] = coorsIn[g + 2];
    } else if (tid < 384) {
        int n = (tid - 128) >> 7, t = tid & 127;
        fr[n][t] = feats[(size_t)(node0 + n) * DD + t];
    }
    __syncthreads();

    int j0 = wj * 16 + c16, j1 = j0 + 64;
    float p0x = px[i0],     p0y = py[i0],     p0z = pz[i0];
    float p1x = px[i0 + 1], p1y = py[i0 + 1], p1z = pz[i0 + 1];
    float dxa0 = p0x - px[j0], dya0 = p0y - py[j0], dza0 = p0z - pz[j0];
    float d2a0 = dxa0*dxa0 + dya0*dya0 + dza0*dza0;
    float dxb0 = p0x - px[j1], dyb0 = p0y - py[j1], dzb0 = p0z - pz[j1];
    float d2b0 = dxb0*dxb0 + dyb0*dyb0 + dzb0*dzb0;
    float dxa1 = p1x - px[j0], dya1 = p1y - py[j0], dza1 = p1z - pz[j0];
    float d2a1 = dxa1*dxa1 + dya1*dya1 + dza1*dza1;
    float dxb1 = p1x - px[j1], dyb1 = p1y - py[j1], dzb1 = p1z - pz[j1];
    float d2b1 = dxb1*dxb1 + dyb1*dyb1 + dzb1*dzb1;
    float b2v = wlbL[544 + c16];

    const float* arow0 = Ab + (size_t)node0 * KPAD + quad * 8;
    const float* arow1 = arow0 + KPAD;
    const float* wlr   = wlbL + quad * 8;
    const float* bqw   = Bq + (size_t)b * BQ_B + wj * 512 + lane * 4;
    const short8* wfp  = w2fragL + lane;

    floatx4 acc00 = {0.f,0.f,0.f,0.f}, acc01 = {0.f,0.f,0.f,0.f};
    floatx4 acc10 = {0.f,0.f,0.f,0.f}, acc11 = {0.f,0.f,0.f,0.f};

    int kc0 = kg ? 9 : 0, kc1 = kg ? NCH : 9;
    #pragma unroll 3
    for (int kc = kc0; kc < kc1; ++kc) {
        short8 bf = wfp[kc * 64];
        float4 aA0 = *(const float4*)(arow0 + kc * 32);
        float4 aA1 = *(const float4*)(arow0 + kc * 32 + 4);
        float4 aB0 = *(const float4*)(arow1 + kc * 32);
        float4 aB1 = *(const float4*)(arow1 + kc * 32 + 4);
        float4 l0  = *(const float4*)(wlr + kc * 32);
        float4 l1  = *(const float4*)(wlr + kc * 32 + 4);
        float4 pp0 = *(const float4*)(bqw + (size_t)kc * 4096);
        float4 pp1 = *(const float4*)(bqw + (size_t)kc * 4096 + 256);
        float4 qq0 = *(const float4*)(bqw + (size_t)kc * 4096 + 2048);
        float4 qq1 = *(const float4*)(bqw + (size_t)kc * 4096 + 2304);
        union { unsigned int u[4]; short8 s; } ua, ub, uc, ud;
        silu4pk(fmaf(d2a0, l0.x, aA0.x + pp0.x), fmaf(d2a0, l0.y, aA0.y + pp0.y),
                fmaf(d2a0, l0.z, aA0.z + pp0.z), fmaf(d2a0, l0.w, aA0.w + pp0.w),
                &ua.u[0], &ua.u[1]);
        silu4pk(fmaf(d2a0, l1.x, aA1.x + pp1.x), fmaf(d2a0, l1.y, aA1.y + pp1.y),
                fmaf(d2a0, l1.z, aA1.z + pp1.z), fmaf(d2a0, l1.w, aA1.w + pp1.w),
                &ua.u[2], &ua.u[3]);
        silu4pk(fmaf(d2b0, l0.x, aA0.x + qq0.x), fmaf(d2b0, l0.y, aA0.y + qq0.y),
                fmaf(d2b0, l0.z, aA0.z + qq0.z), fmaf(d2b0, l0.w, aA0.w + qq0.w),
                &ub.u[0], &ub.u[1]);
        silu4pk(fmaf(d2b0, l1.x, aA1.x + qq1.x), fmaf(d2b0, l1.y, aA1.y + qq1.y),
                fmaf(d2b0, l1.z, aA1.z + qq1.z), fmaf(d2b0, l1.w, aA1.w + qq1.w),
                &ub.u[2], &ub.u[3]);
        silu4pk(fmaf(d2a1, l0.x, aB0.x + pp0.x), fmaf(d2a1, l0.y, aB0.y + pp0.y),
                fmaf(d2a1, l0.z, aB0.z + pp0.z), fmaf(d2a1, l0.w, aB0.w + pp0.w),
                &uc.u[0], &uc.u[1]);
        silu4pk(fmaf(d2a1, l1.x, aB1.x + pp1.x), fmaf(d2a1, l1.y, aB1.y + pp1.y),
                fmaf(d2a1, l1.z, aB1.z + pp1.z), fmaf(d2a1, l1.w, aB1.w + pp1.w),
                &uc.u[2], &uc.u[3]);
        silu4pk(fmaf(d2b1, l0.x, aB0.x + qq0.x), fmaf(d2b1, l0.y, aB0.y + qq0.y),
                fmaf(d2b1, l0.z, aB0.z + qq0.z), fmaf(d2b1, l0.w, aB0.w + qq0.w),
                &ud.u[0], &ud.u[1]);
        silu4pk(fmaf(d2b1, l1.x, aB1.x + qq1.x), fmaf(d2b1, l1.y, aB1.y + qq1.y),
                fmaf(d2b1, l1.z, aB1.z + qq1.z), fmaf(d2b1, l1.w, aB1.w + qq1.w),
                &ud.u[2], &ud.u[3]);
        acc00 = __builtin_amdgcn_mfma_f32_16x16x32_bf16(ua.s, bf, acc00, 0, 0, 0);
        acc01 = __builtin_amdgcn_mfma_f32_16x16x32_bf16(ub.s, bf, acc01, 0, 0, 0);
        acc10 = __builtin_amdgcn_mfma_f32_16x16x32_bf16(uc.s, bf, acc10, 0, 0, 0);
        acc11 = __builtin_amdgcn_mfma_f32_16x16x32_bf16(ud.s, bf, acc11, 0, 0, 0);
    }

    if (kg == 0) {
        #pragma unroll
        for (int r = 0; r < 4; ++r) {
            int jl = (wj * 16 + quad * 4 + r) * 17 + c16;
            Ms[0][jl]           = acc00[r];
            Ms[0][jl + 64 * 17] = acc01[r];
            Ms[1][jl]           = acc10[r];
            Ms[1][jl + 64 * 17] = acc11[r];
        }
    }
    __syncthreads();
    if (kg == 1) {
        #pragma unroll
        for (int r = 0; r < 4; ++r) {
            int jl = (wj * 16 + quad * 4 + r) * 17 + c16;
            Ms[0][jl]           = siluf(Ms[0][jl]           + acc00[r] + b2v);
            Ms[0][jl + 64 * 17] = siluf(Ms[0][jl + 64 * 17] + acc01[r] + b2v);
            Ms[1][jl]           = siluf(Ms[1][jl]           + acc10[r] + b2v);
            Ms[1][jl + 64 * 17] = siluf(Ms[1][jl + 64 * 17] + acc11[r] + b2v);
        }
    }
    __syncthreads();

    {   // m_i partial sums
        int n = tid >> 8, g = (tid >> 4) & 15, c = tid & 15;
        float s = 0.f;
        #pragma unroll
        for (int t = 0; t < 8; ++t) s += Ms[n][(g * 8 + t) * 17 + c];
        msum[n][g][c] = s;
    }
    __syncthreads();

    if (tid < 32) {
        int n = tid >> 4, c = tid & 15;
        float s = 0.f;
        #pragma unroll
        for (int g = 0; g < 16; ++g) s += msum[n][g][c];
        ni[n][128 + c] = s;
    }
    if (tid < 128) {   // LayerNorm
        int n = tid >> 6; int l6 = tid & 63;
        unsigned int lnoff = layer * DD;
        float v0 = fr[n][l6], v1 = fr[n][l6 + 64];
        float s1 = v0 + v1, s2 = v0 * v0 + v1 * v1;
        #pragma unroll
        for (int off = 32; off >= 1; off >>= 1) {
            s1 += __shfl_xor(s1, off, 64);
            s2 += __shfl_xor(s2, off, 64);
        }
        float mu  = s1 * (1.0f / 128.0f);
        float var = s2 * (1.0f / 128.0f) - mu * mu;
        float rs  = rsqrtf(var + 1e-5f);
        ni[n][l6]      = (v0 - mu) * rs * loadf(gln, lnoff + l6, isbf)
                       + loadf(bln, lnoff + l6, isbf);
        ni[n][l6 + 64] = (v1 - mu) * rs * loadf(gln, lnoff + l6 + 64, isbf)
                       + loadf(bln, lnoff + l6 + 64, isbf);
    }

    {   // coors-MLP
        int n = tid >> 8, j = tid & 127, hf = (tid >> 7) & 1;
        float mv[16];
        #pragma unroll
        for (int c = 0; c < 16; ++c) mv[c] = Ms[n][j * 17 + c];
        float cwacc = hf ? 0.f : cpk[1152];
        #pragma unroll 2
        for (int hi = 0; hi < 32; ++hi) {
            int hh = (hf << 5) + hi;
            const float4* q = (const float4*)(cpk + hh * 16);
            float4 q0 = q[0], q1 = q[1], q2 = q[2], q3 = q[3];
            float t = cpk[1024 + hh]
                + mv[0]*q0.x + mv[1]*q0.y + mv[2]*q0.z + mv[3]*q0.w
                + mv[4]*q1.x + mv[5]*q1.y + mv[6]*q1.z + mv[7]*q1.w
                + mv[8]*q2.x + mv[9]*q2.y + mv[10]*q2.z + mv[11]*q2.w
                + mv[12]*q3.x + mv[13]*q3.y + mv[14]*q3.z + mv[15]*q3.w;
            cwacc += siluf(t) * cpk[1088 + hh];
        }
        cwf[n][hf][j] = cwacc;
    }
    __syncthreads();

    if (tid < 256) {   // coors reduce
        int n = tid >> 7, j = tid & 127;
        float cw = cwf[n][0][j] + cwf[n][1][j];
        float pnx = (n == 0) ? p0x : p1x;
        float pny = (n == 0) ? p0y : p1y;
        float pnz = (n == 0) ? p0z : p1z;
        float vx = cw * (pnx - px[j]), vy = cw * (pny - py[j]),
              vz = cw * (pnz - pz[j]);
        #pragma unroll
        for (int off = 32; off >= 1; off >>= 1) {
            vx += __shfl_xor(vx, off, 64);
            vy += __shfl_xor(vy, off, 64);
            vz += __shfl_xor(vz, off, 64);
        }
        if (lane == 0) { red[w][0] = vx; red[w][1] = vy; red[w][2] = vz; }
    }

    {   // node-MLP hidden
        int n = tid >> 8, h = tid & 255;
        size_t w1off = (size_t)layer * 144 * 256;
        float acc = loadf(b1r, layer * 256 + h, isbf);
        if (isbf) {
            const unsigned short* wp = (const unsigned short*)w1r + w1off + h;
            #pragma unroll 8
            for (int d = 0; d < 144; ++d) acc += ni[n][d] * b2f(wp[(size_t)d * 256]);
        } else {
            const float* wp = (const float*)w1r + w1off + h;
            #pragma unroll 8
            for (int d = 0; d < 144; ++d) acc += ni[n][d] * wp[(size_t)d * 256];
        }
        hid[n][h] = siluf(acc);
    }
    __syncthreads();

    if (tid < 6) {
        int n = tid / 3, c = tid - n * 3;
        int nd = node0 + n;
        coorsOut[nd * 3 + c] = coorsIn[nd * 3 + c]
            + red[n * 2][c] + red[n * 2 + 1][c];
    }
    {   // node-MLP out
        int n = tid >> 8, d = tid & 127, hf = (tid >> 7) & 1;
        size_t w2off = (size_t)layer * 256 * 128;
        float acc = hf ? 0.f : loadf(b2r, layer * 128 + d, isbf);
        if (isbf) {
            const unsigned short* wp = (const unsigned short*)w2r + w2off
                                     + (size_t)hf * 128 * 128 + d;
            #pragma unroll 8
            for (int h = 0; h < 128; ++h) acc += hid[n][hf * 128 + h] * b2f(wp[(size_t)h * 128]);
        } else {
            const float* wp = (const float*)w2r + w2off + (size_t)hf * 128 * 128 + d;
            #pragma unroll 8
            for (int h = 0; h < 128; ++h) acc += hid[n][hf * 128 + h] * wp[(size_t)h * 128];
        }
        part[n][hf][d] = acc;
    }
    __syncthreads();
    if (tid < 256) {
        int n = tid >> 7, d = tid & 127;
        float v = fr[n][d] + part[n][0][d] + part[n][1][d];
        feats[(size_t)(node0 + n) * DD + d] = v;
        fb16[(size_t)(node0 + n) * DD + d] = f2b(v);
    }
}

// ---------------- K4: mean pool ----------------
__global__ __launch_bounds__(128) void k4_pool(
    const float* __restrict__ feats, void* __restrict__ out,
    const int* __restrict__ flagp) {
    int b = blockIdx.x, d = threadIdx.x;
    float s = 0.f;
    for (int n = 0; n < NN; ++n) s += feats[((size_t)(b * NN + n)) * DD + d];
    float v = s * (1.0f / 128.0f);
    if (*flagp) ((unsigned short*)out)[b * DD + d] = f2b(v);
    else        ((float*)out)[b * DD + d] = v;
}

// ---------------- launch ----------------
extern "C" void kernel_launch(void* const* d_in, const int* in_sizes, int n_in,
                              void* d_out, int out_size, void* d_ws, size_t ws_size,
                              hipStream_t stream) {
    const int* z = (const int*)d_in[0];
    const void* pos  = d_in[1];
    const void* emb  = d_in[3];
    const void* e_w1 = d_in[4];
    const void* e_b1 = d_in[5];
    const void* e_w2 = d_in[6];
    const void* e_b2 = d_in[7];
    const void* c_w1 = d_in[8];
    const void* c_b1 = d_in[9];
    const void* c_w2 = d_in[10];
    const void* c_b2 = d_in[11];
    const void* ln_g = d_in[12];
    const void* ln_b = d_in[13];
    const void* n_w1 = d_in[14];
    const void* n_b1 = d_in[15];
    const void* n_w2 = d_in[16];
    const void* n_b2 = d_in[17];

    float* ws     = (float*)d_ws;
    float* feats  = ws + OFF_FEATS;
    float* coorsA = ws + OFF_COORSA;
    float* coorsB = ws + OFF_COORSB;
    float* Ab     = ws + OFF_AB;
    float* Bq     = ws + OFF_BQ;
    float* cpk    = ws + OFF_CPK;
    float* wlb    = ws + OFF_WLB;
    int4*  w2f    = (int4*)(ws + OFF_W2F);
    int*   flag   = (int*)(ws + OFF_FLAG);
    unsigned short* fb16 = (unsigned short*)(ws + OFF_FB16);
    int4*  w1f    = (int4*)(ws + OFF_W1F);

    k_init<<<856, 256, 0, stream>>>(
        z, pos, emb, e_w1, e_w2, e_b2, c_w1, c_b1, c_w2, c_b2,
        feats, fb16, coorsA, wlb, w2f, w1f, cpk, flag);

    float* cin = coorsA; float* cout = coorsB;
    for (int l = 0; l < DEPTH; ++l) {
        k1_ab<<<272, 256, 0, stream>>>(
            fb16, w1f + (size_t)l * 68 * 4 * 64, e_b1,
            (unsigned int)(l * H1), Ab, Bq, flag);
        k2_pair<<<BATCH * NN / 2, 512, 0, stream>>>(
            Ab, Bq, cin, cout, feats, fb16,
            wlb + l * 560, (const short8*)(w2f + (size_t)l * NCH * 64),
            cpk + (size_t)l * 1216,
            ln_g, ln_b, n_w1, n_b1, n_w2, n_b2,
            (unsigned int)l, flag);
        float* t = cin; cin = cout; cout = t;
    }
    k4_pool<<<BATCH, 128, 0, stream>>>(feats, d_out, flag);
}

// Round 16
// 317.738 us; speedup vs baseline: 1.0454x; 1.0454x over previous
//
#include <hip/hip_runtime.h>

// ---------------- constants ----------------
#define BATCH 8
#define NN    128
#define DD    128
#define MM    16
#define DEPTH 4
#define EIN   257      // 2*D+1
#define H1    514      // 2*EIN
#define KPAD  544      // H1 padded to 17 chunks of 32
#define NCH   17
#define NODES (BATCH*NN)   // 1024
#define BQ_B  69632        // per-batch Bq floats: 17*4096

typedef __attribute__((ext_vector_type(8))) short short8;   // 8 bf16
typedef __attribute__((ext_vector_type(4))) float floatx4;  // MFMA C/D

__device__ __forceinline__ float b2f(unsigned short u) {
    return __uint_as_float(((unsigned int)u) << 16);
}
__device__ __forceinline__ unsigned short f2b(float f) {
    unsigned int x = __float_as_uint(f);
    unsigned int r = (x + 0x7fffu + ((x >> 16) & 1u)) >> 16;
    return (unsigned short)r;
}
// silu: v_exp_f32 + v_rcp_f32 (r15's shared-rcp variant REGRESSED - reverted)
__device__ __forceinline__ float siluf(float x) {
    float t = __builtin_amdgcn_exp2f(x * -1.442695040888963f);
    return x * __builtin_amdgcn_rcpf(1.0f + t);
}
__device__ __forceinline__ float loadf(const void* p, size_t idx, int isbf) {
    return isbf ? b2f(((const unsigned short*)p)[idx]) : ((const float*)p)[idx];
}
// 2xf32 -> packed bf16 (round-half-up via +0x8000 then byte-perm)
__device__ __forceinline__ unsigned int pk2(float x, float y) {
    unsigned int xb = __float_as_uint(x) + 0x8000u;
    unsigned int yb = __float_as_uint(y) + 0x8000u;
    return __builtin_amdgcn_perm(yb, xb, 0x07060302);
}
__device__ __forceinline__ unsigned int h2pk(float d2, float l0, float l1,
                                             float s0, float s1) {
    float h0 = siluf(fmaf(d2, l0, s0));
    float h1 = siluf(fmaf(d2, l1, s1));
    return pk2(h0, h1);
}

// ---------------- workspace layout (floats) ----------------
#define OFF_FEATS   0
#define OFF_COORSA  131072
#define OFF_COORSB  134144
#define OFF_AB      137216      // Ab [1024][544]
// Bq LANE-LINEAR layout: [8 b][17 kc][8 jt][2 hsel][64 lane][4 t]
#define OFF_BQ      694272
#define OFF_CPK     1267712     // [4][1216]
#define OFF_WLB     1272576     // [4][560]
#define OFF_W2F     1274816     // [4][17][64] int4
#define OFF_FLAG    1292224
#define OFF_FB16    1292228     // u16[1024][128]
#define OFF_W1F     1357764     // int4[4][68][4][64]

// ---------------- k_init ----------------
__global__ __launch_bounds__(256) void k_init(
    const int* __restrict__ z, const void* __restrict__ pos,
    const void* __restrict__ emb,
    const void* __restrict__ e_w1, const void* __restrict__ e_w2,
    const void* __restrict__ e_b2,
    const void* __restrict__ c_w1, const void* __restrict__ c_b1,
    const void* __restrict__ c_w2, const void* __restrict__ c_b2,
    float* __restrict__ feats, unsigned short* __restrict__ fb16,
    float* __restrict__ coorsA,
    float* __restrict__ wlb, int4* __restrict__ w2frag,
    int4* __restrict__ w1frag,
    float* __restrict__ cpack, int* __restrict__ flag) {
    __shared__ int sfl;
    int tid = threadIdx.x, bx = blockIdx.x;
    if (tid < 64) {
        float f = fabsf(__uint_as_float(((const unsigned int*)pos)[tid]));
        bool ok = (f == 0.f) || (f > 1e-8f && f < 1e8f);
        unsigned long long v = __ballot(ok);
        if (tid == 0) sfl = (__builtin_popcountll(v) >= 32) ? 0 : 1;
    }
    __syncthreads();
    int isbf = sfl;
    if (bx == 0 && tid == 0) *flag = isbf;
    if (bx < 512) {
        int node = 2 * bx + (tid >> 7), t = tid & 127;
        int zi = z[node];
        float v = loadf(emb, (size_t)zi * DD + t, isbf);
        feats[node * DD + t] = v;
        fb16[node * DD + t] = f2b(v);
        if (t < 3) coorsA[node * 3 + t] = loadf(pos, node * 3 + t, isbf);
    } else if (bx < 580) {
        int p = bx - 512;
        int layer = p / NCH, kc = p % NCH;
        if (tid < 64) {
            int quad = tid >> 4, c = tid & 15;
            size_t w2base = (size_t)layer * H1 * MM;
            unsigned int u[4];
            #pragma unroll
            for (int pp = 0; pp < 4; ++pp) {
                int k0 = kc * 32 + quad * 8 + 2 * pp, k1 = k0 + 1;
                float f0 = (k0 < H1) ? loadf(e_w2, w2base + (size_t)k0 * MM + c, isbf) : 0.f;
                float f1 = (k1 < H1) ? loadf(e_w2, w2base + (size_t)k1 * MM + c, isbf) : 0.f;
                u[pp] = pk2(f0, f1);
            }
            w2frag[(layer * NCH + kc) * 64 + tid] =
                make_int4((int)u[0], (int)u[1], (int)u[2], (int)u[3]);
            if (kc == 0) {
                size_t wlbase = ((size_t)layer * EIN + 256) * H1;
                for (int t = tid; t < KPAD; t += 64)
                    wlb[layer * 560 + t] = (t < H1) ? loadf(e_w1, wlbase + t, isbf) : 0.f;
                if (tid < 16)
                    wlb[layer * 560 + 544 + tid] = loadf(e_b2, layer * MM + tid, isbf);
            }
        }
    } else if (bx < 584) {
        int l = bx - 580;
        for (int idx = tid; idx < 1024; idx += 256) {
            int c = idx >> 6, hh = idx & 63;
            cpack[l * 1216 + hh * 16 + c] = loadf(c_w1, l * 1024 + c * 64 + hh, isbf);
        }
        if (tid < 64)        cpack[l * 1216 + 1024 + tid] = loadf(c_b1, l * 64 + tid, isbf);
        else if (tid < 128)  cpack[l * 1216 + 1088 + tid - 64] = loadf(c_w2, l * 64 + tid - 64, isbf);
        else if (tid == 128) cpack[l * 1216 + 1152] = loadf(c_b2, l, isbf);
    } else {
        int p = bx - 584;
        int l = p / 68, nt = p % 68;
        int kcd = tid >> 6, lane = tid & 63;
        int quad = lane >> 4, c16 = lane & 15;
        int n_local = nt * 16 + c16;
        int half = n_local >= KPAD;
        int k_out = n_local - (half ? KPAD : 0);
        size_t wbase = (size_t)l * EIN * H1 + (size_t)(half ? 128 : 0) * H1 + k_out;
        unsigned int u[4];
        #pragma unroll
        for (int pp = 0; pp < 4; ++pp) {
            int d0 = kcd * 32 + quad * 8 + 2 * pp;
            float f0 = (k_out < H1) ? loadf(e_w1, wbase + (size_t)d0 * H1, isbf) : 0.f;
            float f1 = (k_out < H1) ? loadf(e_w1, wbase + (size_t)(d0 + 1) * H1, isbf) : 0.f;
            u[pp] = pk2(f0, f1);
        }
        w1frag[((size_t)(l * 68 + nt) * 4 + kcd) * 64 + lane] =
            make_int4((int)u[0], (int)u[1], (int)u[2], (int)u[3]);
    }
}

// ---------------- K1: MFMA GEMM (r14 1088-block config - best measured) ----
__global__ __launch_bounds__(256) void k1_ab(
    const unsigned short* __restrict__ fb16, const int4* __restrict__ w1f,
    const void* __restrict__ b1raw, unsigned int b1off,
    float* __restrict__ Ab, float* __restrict__ Bq,
    const int* __restrict__ flagp) {
    int bx = blockIdx.x;
    int mt = bx & 63, ng = bx >> 6;
    int tid = threadIdx.x, w = tid >> 6, lane = tid & 63;
    int quad = lane >> 4, c16 = lane & 15;
    int isbf = *flagp;
    int ntile = ng * 4 + w;
    int n_local = ntile * 16 + c16;
    int half = n_local >= KPAD;
    int k_out = n_local - (half ? KPAD : 0);

    const unsigned short* ap = fb16 + (size_t)(mt * 16 + c16) * DD + quad * 8;
    const int4* bp = w1f + (size_t)ntile * 4 * 64 + lane;
    floatx4 acc = {0.f, 0.f, 0.f, 0.f};
    #pragma unroll
    for (int kcd = 0; kcd < 4; ++kcd) {
        short8 af = *(const short8*)(ap + kcd * 32);
        union { int4 i4; short8 s; } bf;
        bf.i4 = bp[kcd * 64];
        acc = __builtin_amdgcn_mfma_f32_16x16x32_bf16(af, bf.s, acc, 0, 0, 0);
    }
    if (!half) {
        float bias = (k_out < H1) ? loadf(b1raw, b1off + k_out, isbf) : 0.f;
        #pragma unroll
        for (int r = 0; r < 4; ++r)
            Ab[(size_t)(mt * 16 + quad * 4 + r) * KPAD + k_out] = acc[r] + bias;
    } else {
        int kc = k_out >> 5, kk = k_out & 31;
        int qd = kk >> 3, hsel = (kk >> 2) & 1, tt = k_out & 3;
        #pragma unroll
        for (int r = 0; r < 4; ++r) {
            int node = mt * 16 + quad * 4 + r;
            int bb = node >> 7, j = node & 127;
            int jt = j >> 4, lj = qd * 16 + (j & 15);
            Bq[(size_t)bb * BQ_B + kc * 4096 + jt * 512 + hsel * 256
               + lj * 4 + tt] = acc[r];
        }
    }
}

// ---------------- K2f: compile-time-unrolled K-loop halves -----------------
#define K2_CHUNK(kc_) {                                                       \
    short8 bf = wfp[(kc_) * 64];                                              \
    float4 aA0 = *(const float4*)(arow0 + (kc_) * 32);                        \
    float4 aA1 = *(const float4*)(arow0 + (kc_) * 32 + 4);                    \
    float4 aB0 = *(const float4*)(arow1 + (kc_) * 32);                        \
    float4 aB1 = *(const float4*)(arow1 + (kc_) * 32 + 4);                    \
    float4 l0  = *(const float4*)(wlr + (kc_) * 32);                          \
    float4 l1  = *(const float4*)(wlr + (kc_) * 32 + 4);                      \
    float4 pp0 = *(const float4*)(bqw + (size_t)(kc_) * 4096);                \
    float4 pp1 = *(const float4*)(bqw + (size_t)(kc_) * 4096 + 256);          \
    float4 qq0 = *(const float4*)(bqw + (size_t)(kc_) * 4096 + 2048);         \
    float4 qq1 = *(const float4*)(bqw + (size_t)(kc_) * 4096 + 2304);         \
    union { unsigned int u[4]; short8 s; } ua, ub, uc, ud;                    \
    ua.u[0] = h2pk(d2a0, l0.x, l0.y, aA0.x + pp0.x, aA0.y + pp0.y);          \
    ua.u[1] = h2pk(d2a0, l0.z, l0.w, aA0.z + pp0.z, aA0.w + pp0.w);          \
    ua.u[2] = h2pk(d2a0, l1.x, l1.y, aA1.x + pp1.x, aA1.y + pp1.y);          \
    ua.u[3] = h2pk(d2a0, l1.z, l1.w, aA1.z + pp1.z, aA1.w + pp1.w);          \
    ub.u[0] = h2pk(d2b0, l0.x, l0.y, aA0.x + qq0.x, aA0.y + qq0.y);          \
    ub.u[1] = h2pk(d2b0, l0.z, l0.w, aA0.z + qq0.z, aA0.w + qq0.w);          \
    ub.u[2] = h2pk(d2b0, l1.x, l1.y, aA1.x + qq1.x, aA1.y + qq1.y);          \
    ub.u[3] = h2pk(d2b0, l1.z, l1.w, aA1.z + qq1.z, aA1.w + qq1.w);          \
    uc.u[0] = h2pk(d2a1, l0.x, l0.y, aB0.x + pp0.x, aB0.y + pp0.y);          \
    uc.u[1] = h2pk(d2a1, l0.z, l0.w, aB0.z + pp0.z, aB0.w + pp0.w);          \
    uc.u[2] = h2pk(d2a1, l1.x, l1.y, aB1.x + pp1.x, aB1.y + pp1.y);          \
    uc.u[3] = h2pk(d2a1, l1.z, l1.w, aB1.z + pp1.z, aB1.w + pp1.w);          \
    ud.u[0] = h2pk(d2b1, l0.x, l0.y, aB0.x + qq0.x, aB0.y + qq0.y);          \
    ud.u[1] = h2pk(d2b1, l0.z, l0.w, aB0.z + qq0.z, aB0.w + qq0.w);          \
    ud.u[2] = h2pk(d2b1, l1.x, l1.y, aB1.x + qq1.x, aB1.y + qq1.y);          \
    ud.u[3] = h2pk(d2b1, l1.z, l1.w, aB1.z + qq1.z, aB1.w + qq1.w);          \
    acc00 = __builtin_amdgcn_mfma_f32_16x16x32_bf16(ua.s, bf, acc00, 0, 0, 0);\
    acc01 = __builtin_amdgcn_mfma_f32_16x16x32_bf16(ub.s, bf, acc01, 0, 0, 0);\
    acc10 = __builtin_amdgcn_mfma_f32_16x16x32_bf16(uc.s, bf, acc10, 0, 0, 0);\
    acc11 = __builtin_amdgcn_mfma_f32_16x16x32_bf16(ud.s, bf, acc11, 0, 0, 0);}

__global__ __launch_bounds__(512, 4) void k2_pair(
    const float* __restrict__ Ab, const float* __restrict__ Bq,
    const float* __restrict__ coorsIn, float* __restrict__ coorsOut,
    float* __restrict__ feats, unsigned short* __restrict__ fb16,
    const float* __restrict__ wlbL,     // [560]: wl[544] + b2[16]
    const short8* __restrict__ w2fragL, // [17][64] bf16 frags
    const float* __restrict__ cpk,      // [1216]
    const void* __restrict__ gln, const void* __restrict__ bln,
    const void* __restrict__ w1r, const void* __restrict__ b1r,
    const void* __restrict__ w2r, const void* __restrict__ b2r,
    unsigned int layer, const int* __restrict__ flagp) {
    __shared__ float Ms[2][128 * 17];
    __shared__ float px[128], py[128], pz[128];
    __shared__ float msum[2][16][16];
    __shared__ float cwf[2][2][128];
    __shared__ float red[4][3];
    __shared__ float fr[2][128];
    __shared__ float ni[2][144];
    __shared__ float hid[2][256];
    __shared__ float part[2][2][128];
    int tid = threadIdx.x;
    int b = blockIdx.x & 7, ip = blockIdx.x >> 3;   // XCD-aware swizzle
    int i0 = ip * 2;
    int node0 = b * NN + i0;
    int w = tid >> 6, lane = tid & 63;
    int quad = lane >> 4, c16 = lane & 15;
    int kg = w >> 2, wj = w & 3;
    int isbf = *flagp;

    if (tid < 128) {
        int g = (b * NN + tid) * 3;
        px[tid] = coorsIn[g]; py[tid] = coorsIn[g + 1]; pz[tid] = coorsIn[g + 2];
    } else if (tid < 384) {
        int n = (tid - 128) >> 7, t = tid & 127;
        fr[n][t] = feats[(size_t)(node0 + n) * DD + t];
    }
    __syncthreads();

    int j0 = wj * 16 + c16, j1 = j0 + 64;
    float p0x = px[i0],     p0y = py[i0],     p0z = pz[i0];
    float p1x = px[i0 + 1], p1y = py[i0 + 1], p1z = pz[i0 + 1];
    float dxa0 = p0x - px[j0], dya0 = p0y - py[j0], dza0 = p0z - pz[j0];
    float d2a0 = dxa0*dxa0 + dya0*dya0 + dza0*dza0;
    float dxb0 = p0x - px[j1], dyb0 = p0y - py[j1], dzb0 = p0z - pz[j1];
    float d2b0 = dxb0*dxb0 + dyb0*dyb0 + dzb0*dzb0;
    float dxa1 = p1x - px[j0], dya1 = p1y - py[j0], dza1 = p1z - pz[j0];
    float d2a1 = dxa1*dxa1 + dya1*dya1 + dza1*dza1;
    float dxb1 = p1x - px[j1], dyb1 = p1y - py[j1], dzb1 = p1z - pz[j1];
    float d2b1 = dxb1*dxb1 + dyb1*dyb1 + dzb1*dzb1;
    float b2v = wlbL[544 + c16];

    const float* arow0 = Ab + (size_t)node0 * KPAD + quad * 8;
    const float* arow1 = arow0 + KPAD;
    const float* wlr   = wlbL + quad * 8;
    const float* bqw   = Bq + (size_t)b * BQ_B + wj * 512 + lane * 4;
    const short8* wfp  = w2fragL + lane;

    floatx4 acc00 = {0.f,0.f,0.f,0.f}, acc01 = {0.f,0.f,0.f,0.f};
    floatx4 acc10 = {0.f,0.f,0.f,0.f}, acc11 = {0.f,0.f,0.f,0.f};

    // compile-time-specialized K-loop halves: full static scheduling window
    if (kg == 0) {
        K2_CHUNK(0) K2_CHUNK(1) K2_CHUNK(2) K2_CHUNK(3) K2_CHUNK(4)
        K2_CHUNK(5) K2_CHUNK(6) K2_CHUNK(7) K2_CHUNK(8)
    } else {
        K2_CHUNK(9) K2_CHUNK(10) K2_CHUNK(11) K2_CHUNK(12)
        K2_CHUNK(13) K2_CHUNK(14) K2_CHUNK(15) K2_CHUNK(16)
    }

    if (kg == 0) {
        #pragma unroll
        for (int r = 0; r < 4; ++r) {
            int jl = (wj * 16 + quad * 4 + r) * 17 + c16;
            Ms[0][jl]           = acc00[r];
            Ms[0][jl + 64 * 17] = acc01[r];
            Ms[1][jl]           = acc10[r];
            Ms[1][jl + 64 * 17] = acc11[r];
        }
    }
    __syncthreads();
    if (kg == 1) {
        #pragma unroll
        for (int r = 0; r < 4; ++r) {
            int jl = (wj * 16 + quad * 4 + r) * 17 + c16;
            Ms[0][jl]           = siluf(Ms[0][jl]           + acc00[r] + b2v);
            Ms[0][jl + 64 * 17] = siluf(Ms[0][jl + 64 * 17] + acc01[r] + b2v);
            Ms[1][jl]           = siluf(Ms[1][jl]           + acc10[r] + b2v);
            Ms[1][jl + 64 * 17] = siluf(Ms[1][jl + 64 * 17] + acc11[r] + b2v);
        }
    }
    __syncthreads();

    {   // m_i partial sums
        int n = tid >> 8, g = (tid >> 4) & 15, c = tid & 15;
        float s = 0.f;
        #pragma unroll
        for (int t = 0; t < 8; ++t) s += Ms[n][(g * 8 + t) * 17 + c];
        msum[n][g][c] = s;
    }
    __syncthreads();

    if (tid < 32) {
        int n = tid >> 4, c = tid & 15;
        float s = 0.f;
        #pragma unroll
        for (int g = 0; g < 16; ++g) s += msum[n][g][c];
        ni[n][128 + c] = s;
    }
    if (tid < 128) {   // LayerNorm
        int n = tid >> 6; int l6 = tid & 63;
        unsigned int lnoff = layer * DD;
        float v0 = fr[n][l6], v1 = fr[n][l6 + 64];
        float s1 = v0 + v1, s2 = v0 * v0 + v1 * v1;
        #pragma unroll
        for (int off = 32; off >= 1; off >>= 1) {
            s1 += __shfl_xor(s1, off, 64);
            s2 += __shfl_xor(s2, off, 64);
        }
        float mu  = s1 * (1.0f / 128.0f);
        float var = s2 * (1.0f / 128.0f) - mu * mu;
        float rs  = rsqrtf(var + 1e-5f);
        ni[n][l6]      = (v0 - mu) * rs * loadf(gln, lnoff + l6, isbf)
                       + loadf(bln, lnoff + l6, isbf);
        ni[n][l6 + 64] = (v1 - mu) * rs * loadf(gln, lnoff + l6 + 64, isbf)
                       + loadf(bln, lnoff + l6 + 64, isbf);
    }

    {   // coors-MLP
        int n = tid >> 8, j = tid & 127, hf = (tid >> 7) & 1;
        float mv[16];
        #pragma unroll
        for (int c = 0; c < 16; ++c) mv[c] = Ms[n][j * 17 + c];
        float cwacc = hf ? 0.f : cpk[1152];
        #pragma unroll 2
        for (int hi = 0; hi < 32; ++hi) {
            int hh = (hf << 5) + hi;
            const float4* q = (const float4*)(cpk + hh * 16);
            float4 q0 = q[0], q1 = q[1], q2 = q[2], q3 = q[3];
            float t = cpk[1024 + hh]
                + mv[0]*q0.x + mv[1]*q0.y + mv[2]*q0.z + mv[3]*q0.w
                + mv[4]*q1.x + mv[5]*q1.y + mv[6]*q1.z + mv[7]*q1.w
                + mv[8]*q2.x + mv[9]*q2.y + mv[10]*q2.z + mv[11]*q2.w
                + mv[12]*q3.x + mv[13]*q3.y + mv[14]*q3.z + mv[15]*q3.w;
            cwacc += siluf(t) * cpk[1088 + hh];
        }
        cwf[n][hf][j] = cwacc;
    }
    __syncthreads();

    if (tid < 256) {   // coors reduce
        int n = tid >> 7, j = tid & 127;
        float cw = cwf[n][0][j] + cwf[n][1][j];
        float pnx = (n == 0) ? p0x : p1x;
        float pny = (n == 0) ? p0y : p1y;
        float pnz = (n == 0) ? p0z : p1z;
        float vx = cw * (pnx - px[j]), vy = cw * (pny - py[j]),
              vz = cw * (pnz - pz[j]);
        #pragma unroll
        for (int off = 32; off >= 1; off >>= 1) {
            vx += __shfl_xor(vx, off, 64);
            vy += __shfl_xor(vy, off, 64);
            vz += __shfl_xor(vz, off, 64);
        }
        if (lane == 0) { red[w][0] = vx; red[w][1] = vy; red[w][2] = vz; }
    }

    {   // node-MLP hidden
        int n = tid >> 8, h = tid & 255;
        size_t w1off = (size_t)layer * 144 * 256;
        float acc = loadf(b1r, layer * 256 + h, isbf);
        if (isbf) {
            const unsigned short* wp = (const unsigned short*)w1r + w1off + h;
            #pragma unroll 8
            for (int d = 0; d < 144; ++d) acc += ni[n][d] * b2f(wp[(size_t)d * 256]);
        } else {
            const float* wp = (const float*)w1r + w1off + h;
            #pragma unroll 8
            for (int d = 0; d < 144; ++d) acc += ni[n][d] * wp[(size_t)d * 256];
        }
        hid[n][h] = siluf(acc);
    }
    __syncthreads();

    if (tid < 6) {
        int n = tid / 3, c = tid - n * 3;
        int nd = node0 + n;
        coorsOut[nd * 3 + c] = coorsIn[nd * 3 + c]
            + red[n * 2][c] + red[n * 2 + 1][c];
    }
    {   // node-MLP out
        int n = tid >> 8, d = tid & 127, hf = (tid >> 7) & 1;
        size_t w2off = (size_t)layer * 256 * 128;
        float acc = hf ? 0.f : loadf(b2r, layer * 128 + d, isbf);
        if (isbf) {
            const unsigned short* wp = (const unsigned short*)w2r + w2off
                                     + (size_t)hf * 128 * 128 + d;
            #pragma unroll 8
            for (int h = 0; h < 128; ++h) acc += hid[n][hf * 128 + h] * b2f(wp[(size_t)h * 128]);
        } else {
            const float* wp = (const float*)w2r + w2off + (size_t)hf * 128 * 128 + d;
            #pragma unroll 8
            for (int h = 0; h < 128; ++h) acc += hid[n][hf * 128 + h] * wp[(size_t)h * 128];
        }
        part[n][hf][d] = acc;
    }
    __syncthreads();
    if (tid < 256) {
        int n = tid >> 7, d = tid & 127;
        float v = fr[n][d] + part[n][0][d] + part[n][1][d];
        feats[(size_t)(node0 + n) * DD + d] = v;
        fb16[(size_t)(node0 + n) * DD + d] = f2b(v);
    }
}

// ---------------- K4: mean pool ----------------
__global__ __launch_bounds__(128) void k4_pool(
    const float* __restrict__ feats, void* __restrict__ out,
    const int* __restrict__ flagp) {
    int b = blockIdx.x, d = threadIdx.x;
    float s = 0.f;
    for (int n = 0; n < NN; ++n) s += feats[((size_t)(b * NN + n)) * DD + d];
    float v = s * (1.0f / 128.0f);
    if (*flagp) ((unsigned short*)out)[b * DD + d] = f2b(v);
    else        ((float*)out)[b * DD + d] = v;
}

// ---------------- launch ----------------
extern "C" void kernel_launch(void* const* d_in, const int* in_sizes, int n_in,
                              void* d_out, int out_size, void* d_ws, size_t ws_size,
                              hipStream_t stream) {
    const int* z = (const int*)d_in[0];
    const void* pos  = d_in[1];
    const void* emb  = d_in[3];
    const void* e_w1 = d_in[4];
    const void* e_b1 = d_in[5];
    const void* e_w2 = d_in[6];
    const void* e_b2 = d_in[7];
    const void* c_w1 = d_in[8];
    const void* c_b1 = d_in[9];
    const void* c_w2 = d_in[10];
    const void* c_b2 = d_in[11];
    const void* ln_g = d_in[12];
    const void* ln_b = d_in[13];
    const void* n_w1 = d_in[14];
    const void* n_b1 = d_in[15];
    const void* n_w2 = d_in[16];
    const void* n_b2 = d_in[17];

    float* ws     = (float*)d_ws;
    float* feats  = ws + OFF_FEATS;
    float* coorsA = ws + OFF_COORSA;
    float* coorsB = ws + OFF_COORSB;
    float* Ab     = ws + OFF_AB;
    float* Bq     = ws + OFF_BQ;
    float* cpk    = ws + OFF_CPK;
    float* wlb    = ws + OFF_WLB;
    int4*  w2f    = (int4*)(ws + OFF_W2F);
    int*   flag   = (int*)(ws + OFF_FLAG);
    unsigned short* fb16 = (unsigned short*)(ws + OFF_FB16);
    int4*  w1f    = (int4*)(ws + OFF_W1F);

    k_init<<<856, 256, 0, stream>>>(
        z, pos, emb, e_w1, e_w2, e_b2, c_w1, c_b1, c_w2, c_b2,
        feats, fb16, coorsA, wlb, w2f, w1f, cpk, flag);

    float* cin = coorsA; float* cout = coorsB;
    for (int l = 0; l < DEPTH; ++l) {
        k1_ab<<<1088, 256, 0, stream>>>(
            fb16, w1f + (size_t)l * 68 * 4 * 64, e_b1,
            (unsigned int)(l * H1), Ab, Bq, flag);
        k2_pair<<<BATCH * NN / 2, 512, 0, stream>>>(
            Ab, Bq, cin, cout, feats, fb16,
            wlb + l * 560, (const short8*)(w2f + (size_t)l * NCH * 64),
            cpk + (size_t)l * 1216,
            ln_g, ln_b, n_w1, n_b1, n_w2, n_b2,
            (unsigned int)l, flag);
        float* t = cin; cin = cout; cout = t;
    }
    k4_pool<<<BATCH, 128, 0, stream>>>(feats, d_out, flag);
}

// Round 17
// 312.885 us; speedup vs baseline: 1.0616x; 1.0155x over previous
//
#include <hip/hip_runtime.h>

// ---------------- constants ----------------
#define BATCH 8
#define NN    128
#define DD    128
#define MM    16
#define DEPTH 4
#define EIN   257      // 2*D+1
#define H1    514      // 2*EIN
#define KPAD  544      // H1 padded to 17 chunks of 32
#define NCH   17
#define NODES (BATCH*NN)   // 1024
#define BQ_B  69632        // per-batch Bq floats: 17*4096
#define NL2E  (-1.442695040888963f)   // -log2(e): folded into A/B/wl
#define NLN2  (-0.6931471805599453f)  // -ln2: undoes the fold post-MFMA

typedef __attribute__((ext_vector_type(8))) short short8;   // 8 bf16
typedef __attribute__((ext_vector_type(4))) float floatx4;  // MFMA C/D

__device__ __forceinline__ float b2f(unsigned short u) {
    return __uint_as_float(((unsigned int)u) << 16);
}
__device__ __forceinline__ unsigned short f2b(float f) {
    unsigned int x = __float_as_uint(f);
    unsigned int r = (x + 0x7fffu + ((x >> 16) & 1u)) >> 16;
    return (unsigned short)r;
}
// scalar silu (epilogue only): v_exp_f32 + v_rcp_f32
__device__ __forceinline__ float siluf(float x) {
    float t = __builtin_amdgcn_exp2f(x * NL2E);
    return x * __builtin_amdgcn_rcpf(1.0f + t);
}
__device__ __forceinline__ float loadf(const void* p, size_t idx, int isbf) {
    return isbf ? b2f(((const unsigned short*)p)[idx]) : ((const float*)p)[idx];
}
// 2xf32 -> packed bf16 (round-half-up via +0x8000 then byte-perm)
__device__ __forceinline__ unsigned int pk2(float x, float y) {
    unsigned int xb = __float_as_uint(x) + 0x8000u;
    unsigned int yb = __float_as_uint(y) + 0x8000u;
    return __builtin_amdgcn_perm(yb, xb, 0x07060302);
}
// main-loop silu on PRE-SCALED input y = -log2e * x:
// h' = y * rcp(1 + exp2(y)) = -log2e * silu(x). 4 VALU/elem (mul eliminated;
// the -log2e scale rides linearly through the MFMA, undone by *NLN2 later).
__device__ __forceinline__ unsigned int h2pk_y(float y0, float y1) {
    float t0 = __builtin_amdgcn_exp2f(y0);
    float t1 = __builtin_amdgcn_exp2f(y1);
    float h0 = y0 * __builtin_amdgcn_rcpf(1.0f + t0);
    float h1 = y1 * __builtin_amdgcn_rcpf(1.0f + t1);
    return pk2(h0, h1);
}

// ---------------- workspace layout (floats) ----------------
#define OFF_FEATS   0
#define OFF_COORSA  131072
#define OFF_COORSB  134144
#define OFF_AB      137216      // Ab [1024][544]  (PRE-SCALED by -log2e)
// Bq LANE-LINEAR layout: [8 b][17 kc][8 jt][2 hsel][64 lane][4 t] (pre-scaled)
#define OFF_BQ      694272
#define OFF_CPK     1267712     // [4][1216]
#define OFF_WLB     1272576     // [4][560]: wl (pre-scaled) + b2 (unscaled)
#define OFF_W2F     1274816     // [4][17][64] int4
#define OFF_FLAG    1292224
#define OFF_FB16    1292228     // u16[1024][128]
#define OFF_W1F     1357764     // int4[4][68][4][64]

// ---------------- k_init ----------------
__global__ __launch_bounds__(256) void k_init(
    const int* __restrict__ z, const void* __restrict__ pos,
    const void* __restrict__ emb,
    const void* __restrict__ e_w1, const void* __restrict__ e_w2,
    const void* __restrict__ e_b2,
    const void* __restrict__ c_w1, const void* __restrict__ c_b1,
    const void* __restrict__ c_w2, const void* __restrict__ c_b2,
    float* __restrict__ feats, unsigned short* __restrict__ fb16,
    float* __restrict__ coorsA,
    float* __restrict__ wlb, int4* __restrict__ w2frag,
    int4* __restrict__ w1frag,
    float* __restrict__ cpack, int* __restrict__ flag) {
    __shared__ int sfl;
    int tid = threadIdx.x, bx = blockIdx.x;
    if (tid < 64) {
        float f = fabsf(__uint_as_float(((const unsigned int*)pos)[tid]));
        bool ok = (f == 0.f) || (f > 1e-8f && f < 1e8f);
        unsigned long long v = __ballot(ok);
        if (tid == 0) sfl = (__builtin_popcountll(v) >= 32) ? 0 : 1;
    }
    __syncthreads();
    int isbf = sfl;
    if (bx == 0 && tid == 0) *flag = isbf;
    if (bx < 512) {
        int node = 2 * bx + (tid >> 7), t = tid & 127;
        int zi = z[node];
        float v = loadf(emb, (size_t)zi * DD + t, isbf);
        feats[node * DD + t] = v;
        fb16[node * DD + t] = f2b(v);
        if (t < 3) coorsA[node * 3 + t] = loadf(pos, node * 3 + t, isbf);
    } else if (bx < 580) {
        int p = bx - 512;
        int layer = p / NCH, kc = p % NCH;
        if (tid < 64) {
            int quad = tid >> 4, c = tid & 15;
            size_t w2base = (size_t)layer * H1 * MM;
            unsigned int u[4];
            #pragma unroll
            for (int pp = 0; pp < 4; ++pp) {
                int k0 = kc * 32 + quad * 8 + 2 * pp, k1 = k0 + 1;
                float f0 = (k0 < H1) ? loadf(e_w2, w2base + (size_t)k0 * MM + c, isbf) : 0.f;
                float f1 = (k1 < H1) ? loadf(e_w2, w2base + (size_t)k1 * MM + c, isbf) : 0.f;
                u[pp] = pk2(f0, f1);
            }
            w2frag[(layer * NCH + kc) * 64 + tid] =
                make_int4((int)u[0], (int)u[1], (int)u[2], (int)u[3]);
            if (kc == 0) {
                size_t wlbase = ((size_t)layer * EIN + 256) * H1;
                for (int t = tid; t < KPAD; t += 64)
                    wlb[layer * 560 + t] =
                        (t < H1) ? NL2E * loadf(e_w1, wlbase + t, isbf) : 0.f;
                if (tid < 16)
                    wlb[layer * 560 + 544 + tid] = loadf(e_b2, layer * MM + tid, isbf);
            }
        }
    } else if (bx < 584) {
        int l = bx - 580;
        for (int idx = tid; idx < 1024; idx += 256) {
            int c = idx >> 6, hh = idx & 63;
            cpack[l * 1216 + hh * 16 + c] = loadf(c_w1, l * 1024 + c * 64 + hh, isbf);
        }
        if (tid < 64)        cpack[l * 1216 + 1024 + tid] = loadf(c_b1, l * 64 + tid, isbf);
        else if (tid < 128)  cpack[l * 1216 + 1088 + tid - 64] = loadf(c_w2, l * 64 + tid - 64, isbf);
        else if (tid == 128) cpack[l * 1216 + 1152] = loadf(c_b2, l, isbf);
    } else {
        int p = bx - 584;
        int l = p / 68, nt = p % 68;
        int kcd = tid >> 6, lane = tid & 63;
        int quad = lane >> 4, c16 = lane & 15;
        int n_local = nt * 16 + c16;
        int half = n_local >= KPAD;
        int k_out = n_local - (half ? KPAD : 0);
        size_t wbase = (size_t)l * EIN * H1 + (size_t)(half ? 128 : 0) * H1 + k_out;
        unsigned int u[4];
        #pragma unroll
        for (int pp = 0; pp < 4; ++pp) {
            int d0 = kcd * 32 + quad * 8 + 2 * pp;
            float f0 = (k_out < H1) ? loadf(e_w1, wbase + (size_t)d0 * H1, isbf) : 0.f;
            float f1 = (k_out < H1) ? loadf(e_w1, wbase + (size_t)(d0 + 1) * H1, isbf) : 0.f;
            u[pp] = pk2(f0, f1);
        }
        w1frag[((size_t)(l * 68 + nt) * 4 + kcd) * 64 + lane] =
            make_int4((int)u[0], (int)u[1], (int)u[2], (int)u[3]);
    }
}

// ---------------- K1: MFMA GEMM; outputs PRE-SCALED by -log2e --------------
__global__ __launch_bounds__(256) void k1_ab(
    const unsigned short* __restrict__ fb16, const int4* __restrict__ w1f,
    const void* __restrict__ b1raw, unsigned int b1off,
    float* __restrict__ Ab, float* __restrict__ Bq,
    const int* __restrict__ flagp) {
    int bx = blockIdx.x;
    int mt = bx & 63, ng = bx >> 6;
    int tid = threadIdx.x, w = tid >> 6, lane = tid & 63;
    int quad = lane >> 4, c16 = lane & 15;
    int isbf = *flagp;
    int ntile = ng * 4 + w;
    int n_local = ntile * 16 + c16;
    int half = n_local >= KPAD;
    int k_out = n_local - (half ? KPAD : 0);

    const unsigned short* ap = fb16 + (size_t)(mt * 16 + c16) * DD + quad * 8;
    const int4* bp = w1f + (size_t)ntile * 4 * 64 + lane;
    floatx4 acc = {0.f, 0.f, 0.f, 0.f};
    #pragma unroll
    for (int kcd = 0; kcd < 4; ++kcd) {
        short8 af = *(const short8*)(ap + kcd * 32);
        union { int4 i4; short8 s; } bf;
        bf.i4 = bp[kcd * 64];
        acc = __builtin_amdgcn_mfma_f32_16x16x32_bf16(af, bf.s, acc, 0, 0, 0);
    }
    if (!half) {
        float bias = (k_out < H1) ? loadf(b1raw, b1off + k_out, isbf) : 0.f;
        #pragma unroll
        for (int r = 0; r < 4; ++r)
            Ab[(size_t)(mt * 16 + quad * 4 + r) * KPAD + k_out] =
                NL2E * (acc[r] + bias);
    } else {
        int kc = k_out >> 5, kk = k_out & 31;
        int qd = kk >> 3, hsel = (kk >> 2) & 1, tt = k_out & 3;
        #pragma unroll
        for (int r = 0; r < 4; ++r) {
            int node = mt * 16 + quad * 4 + r;
            int bb = node >> 7, j = node & 127;
            int jt = j >> 4, lj = qd * 16 + (j & 15);
            Bq[(size_t)bb * BQ_B + kc * 4096 + jt * 512 + hsel * 256
               + lj * 4 + tt] = NL2E * acc[r];
        }
    }
}

// ---------------- K2f: pre-scaled K-loop (no per-element mul) --------------
#define K2_CHUNK(kc_) {                                                       \
    short8 bf = wfp[(kc_) * 64];                                              \
    float4 aA0 = *(const float4*)(arow0 + (kc_) * 32);                        \
    float4 aA1 = *(const float4*)(arow0 + (kc_) * 32 + 4);                    \
    float4 aB0 = *(const float4*)(arow1 + (kc_) * 32);                        \
    float4 aB1 = *(const float4*)(arow1 + (kc_) * 32 + 4);                    \
    float4 l0  = *(const float4*)(wlr + (kc_) * 32);                          \
    float4 l1  = *(const float4*)(wlr + (kc_) * 32 + 4);                      \
    float4 pp0 = *(const float4*)(bqw + (size_t)(kc_) * 4096);                \
    float4 pp1 = *(const float4*)(bqw + (size_t)(kc_) * 4096 + 256);          \
    float4 qq0 = *(const float4*)(bqw + (size_t)(kc_) * 4096 + 2048);         \
    float4 qq1 = *(const float4*)(bqw + (size_t)(kc_) * 4096 + 2304);         \
    union { unsigned int u[4]; short8 s; } ua, ub, uc, ud;                    \
    ua.u[0] = h2pk_y(fmaf(d2a0, l0.x, aA0.x + pp0.x),                         \
                     fmaf(d2a0, l0.y, aA0.y + pp0.y));                        \
    ua.u[1] = h2pk_y(fmaf(d2a0, l0.z, aA0.z + pp0.z),                         \
                     fmaf(d2a0, l0.w, aA0.w + pp0.w));                        \
    ua.u[2] = h2pk_y(fmaf(d2a0, l1.x, aA1.x + pp1.x),                         \
                     fmaf(d2a0, l1.y, aA1.y + pp1.y));                        \
    ua.u[3] = h2pk_y(fmaf(d2a0, l1.z, aA1.z + pp1.z),                         \
                     fmaf(d2a0, l1.w, aA1.w + pp1.w));                        \
    ub.u[0] = h2pk_y(fmaf(d2b0, l0.x, aA0.x + qq0.x),                         \
                     fmaf(d2b0, l0.y, aA0.y + qq0.y));                        \
    ub.u[1] = h2pk_y(fmaf(d2b0, l0.z, aA0.z + qq0.z),                         \
                     fmaf(d2b0, l0.w, aA0.w + qq0.w));                        \
    ub.u[2] = h2pk_y(fmaf(d2b0, l1.x, aA1.x + qq1.x),                         \
                     fmaf(d2b0, l1.y, aA1.y + qq1.y));                        \
    ub.u[3] = h2pk_y(fmaf(d2b0, l1.z, aA1.z + qq1.z),                         \
                     fmaf(d2b0, l1.w, aA1.w + qq1.w));                        \
    uc.u[0] = h2pk_y(fmaf(d2a1, l0.x, aB0.x + pp0.x),                         \
                     fmaf(d2a1, l0.y, aB0.y + pp0.y));                        \
    uc.u[1] = h2pk_y(fmaf(d2a1, l0.z, aB0.z + pp0.z),                         \
                     fmaf(d2a1, l0.w, aB0.w + pp0.w));                        \
    uc.u[2] = h2pk_y(fmaf(d2a1, l1.x, aB1.x + pp1.x),                         \
                     fmaf(d2a1, l1.y, aB1.y + pp1.y));                        \
    uc.u[3] = h2pk_y(fmaf(d2a1, l1.z, aB1.z + pp1.z),                         \
                     fmaf(d2a1, l1.w, aB1.w + pp1.w));                        \
    ud.u[0] = h2pk_y(fmaf(d2b1, l0.x, aB0.x + qq0.x),                         \
                     fmaf(d2b1, l0.y, aB0.y + qq0.y));                        \
    ud.u[1] = h2pk_y(fmaf(d2b1, l0.z, aB0.z + qq0.z),                         \
                     fmaf(d2b1, l0.w, aB0.w + qq0.w));                        \
    ud.u[2] = h2pk_y(fmaf(d2b1, l1.x, aB1.x + qq1.x),                         \
                     fmaf(d2b1, l1.y, aB1.y + qq1.y));                        \
    ud.u[3] = h2pk_y(fmaf(d2b1, l1.z, aB1.z + qq1.z),                         \
                     fmaf(d2b1, l1.w, aB1.w + qq1.w));                        \
    acc00 = __builtin_amdgcn_mfma_f32_16x16x32_bf16(ua.s, bf, acc00, 0, 0, 0);\
    acc01 = __builtin_amdgcn_mfma_f32_16x16x32_bf16(ub.s, bf, acc01, 0, 0, 0);\
    acc10 = __builtin_amdgcn_mfma_f32_16x16x32_bf16(uc.s, bf, acc10, 0, 0, 0);\
    acc11 = __builtin_amdgcn_mfma_f32_16x16x32_bf16(ud.s, bf, acc11, 0, 0, 0);}

__global__ __launch_bounds__(512, 4) void k2_pair(
    const float* __restrict__ Ab, const float* __restrict__ Bq,
    const float* __restrict__ coorsIn, float* __restrict__ coorsOut,
    float* __restrict__ feats, unsigned short* __restrict__ fb16,
    const float* __restrict__ wlbL,     // [560]: wl' [544] + b2[16]
    const short8* __restrict__ w2fragL, // [17][64] bf16 frags
    const float* __restrict__ cpk,      // [1216]
    const void* __restrict__ gln, const void* __restrict__ bln,
    const void* __restrict__ w1r, const void* __restrict__ b1r,
    const void* __restrict__ w2r, const void* __restrict__ b2r,
    unsigned int layer, const int* __restrict__ flagp) {
    __shared__ float Ms[2][128 * 17];
    __shared__ float px[128], py[128], pz[128];
    __shared__ float msum[2][16][16];
    __shared__ float cwf[2][2][128];
    __shared__ float red[4][3];
    __shared__ float fr[2][128];
    __shared__ float ni[2][144];
    __shared__ float hid[2][256];
    __shared__ float part[2][2][128];
    int tid = threadIdx.x;
    int b = blockIdx.x & 7, ip = blockIdx.x >> 3;   // XCD-aware swizzle
    int i0 = ip * 2;
    int node0 = b * NN + i0;
    int w = tid >> 6, lane = tid & 63;
    int quad = lane >> 4, c16 = lane & 15;
    int kg = w >> 2, wj = w & 3;
    int isbf = *flagp;

    if (tid < 128) {
        int g = (b * NN + tid) * 3;
        px[tid] = coorsIn[g]; py[tid] = coorsIn[g + 1]; pz[tid] = coorsIn[g + 2];
    } else if (tid < 384) {
        int n = (tid - 128) >> 7, t = tid & 127;
        fr[n][t] = feats[(size_t)(node0 + n) * DD + t];
    }
    __syncthreads();

    int j0 = wj * 16 + c16, j1 = j0 + 64;
    float p0x = px[i0],     p0y = py[i0],     p0z = pz[i0];
    float p1x = px[i0 + 1], p1y = py[i0 + 1], p1z = pz[i0 + 1];
    float dxa0 = p0x - px[j0], dya0 = p0y - py[j0], dza0 = p0z - pz[j0];
    float d2a0 = dxa0*dxa0 + dya0*dya0 + dza0*dza0;
    float dxb0 = p0x - px[j1], dyb0 = p0y - py[j1], dzb0 = p0z - pz[j1];
    float d2b0 = dxb0*dxb0 + dyb0*dyb0 + dzb0*dzb0;
    float dxa1 = p1x - px[j0], dya1 = p1y - py[j0], dza1 = p1z - pz[j0];
    float d2a1 = dxa1*dxa1 + dya1*dya1 + dza1*dza1;
    float dxb1 = p1x - px[j1], dyb1 = p1y - py[j1], dzb1 = p1z - pz[j1];
    float d2b1 = dxb1*dxb1 + dyb1*dyb1 + dzb1*dzb1;
    float b2v = wlbL[544 + c16];

    const float* arow0 = Ab + (size_t)node0 * KPAD + quad * 8;
    const float* arow1 = arow0 + KPAD;
    const float* wlr   = wlbL + quad * 8;
    const float* bqw   = Bq + (size_t)b * BQ_B + wj * 512 + lane * 4;
    const short8* wfp  = w2fragL + lane;

    floatx4 acc00 = {0.f,0.f,0.f,0.f}, acc01 = {0.f,0.f,0.f,0.f};
    floatx4 acc10 = {0.f,0.f,0.f,0.f}, acc11 = {0.f,0.f,0.f,0.f};

    if (kg == 0) {
        K2_CHUNK(0) K2_CHUNK(1) K2_CHUNK(2) K2_CHUNK(3) K2_CHUNK(4)
        K2_CHUNK(5) K2_CHUNK(6) K2_CHUNK(7) K2_CHUNK(8)
    } else {
        K2_CHUNK(9) K2_CHUNK(10) K2_CHUNK(11) K2_CHUNK(12)
        K2_CHUNK(13) K2_CHUNK(14) K2_CHUNK(15) K2_CHUNK(16)
    }

    if (kg == 0) {
        #pragma unroll
        for (int r = 0; r < 4; ++r) {
            int jl = (wj * 16 + quad * 4 + r) * 17 + c16;
            Ms[0][jl]           = acc00[r];
            Ms[0][jl + 64 * 17] = acc01[r];
            Ms[1][jl]           = acc10[r];
            Ms[1][jl + 64 * 17] = acc11[r];
        }
    }
    __syncthreads();
    if (kg == 1) {
        // undo the -log2e fold (accumulators hold s*(h@W2)): *NLN2, +b2, silu
        #pragma unroll
        for (int r = 0; r < 4; ++r) {
            int jl = (wj * 16 + quad * 4 + r) * 17 + c16;
            Ms[0][jl]           = siluf(fmaf(Ms[0][jl]           + acc00[r], NLN2, b2v));
            Ms[0][jl + 64 * 17] = siluf(fmaf(Ms[0][jl + 64 * 17] + acc01[r], NLN2, b2v));
            Ms[1][jl]           = siluf(fmaf(Ms[1][jl]           + acc10[r], NLN2, b2v));
            Ms[1][jl + 64 * 17] = siluf(fmaf(Ms[1][jl + 64 * 17] + acc11[r], NLN2, b2v));
        }
    }
    __syncthreads();

    {   // m_i partial sums
        int n = tid >> 8, g = (tid >> 4) & 15, c = tid & 15;
        float s = 0.f;
        #pragma unroll
        for (int t = 0; t < 8; ++t) s += Ms[n][(g * 8 + t) * 17 + c];
        msum[n][g][c] = s;
    }
    __syncthreads();

    if (tid < 32) {
        int n = tid >> 4, c = tid & 15;
        float s = 0.f;
        #pragma unroll
        for (int g = 0; g < 16; ++g) s += msum[n][g][c];
        ni[n][128 + c] = s;
    }
    if (tid < 128) {   // LayerNorm
        int n = tid >> 6; int l6 = tid & 63;
        unsigned int lnoff = layer * DD;
        float v0 = fr[n][l6], v1 = fr[n][l6 + 64];
        float s1 = v0 + v1, s2 = v0 * v0 + v1 * v1;
        #pragma unroll
        for (int off = 32; off >= 1; off >>= 1) {
            s1 += __shfl_xor(s1, off, 64);
            s2 += __shfl_xor(s2, off, 64);
        }
        float mu  = s1 * (1.0f / 128.0f);
        float var = s2 * (1.0f / 128.0f) - mu * mu;
        float rs  = rsqrtf(var + 1e-5f);
        ni[n][l6]      = (v0 - mu) * rs * loadf(gln, lnoff + l6, isbf)
                       + loadf(bln, lnoff + l6, isbf);
        ni[n][l6 + 64] = (v1 - mu) * rs * loadf(gln, lnoff + l6 + 64, isbf)
                       + loadf(bln, lnoff + l6 + 64, isbf);
    }

    {   // coors-MLP
        int n = tid >> 8, j = tid & 127, hf = (tid >> 7) & 1;
        float mv[16];
        #pragma unroll
        for (int c = 0; c < 16; ++c) mv[c] = Ms[n][j * 17 + c];
        float cwacc = hf ? 0.f : cpk[1152];
        #pragma unroll 2
        for (int hi = 0; hi < 32; ++hi) {
            int hh = (hf << 5) + hi;
            const float4* q = (const float4*)(cpk + hh * 16);
            float4 q0 = q[0], q1 = q[1], q2 = q[2], q3 = q[3];
            float t = cpk[1024 + hh]
                + mv[0]*q0.x + mv[1]*q0.y + mv[2]*q0.z + mv[3]*q0.w
                + mv[4]*q1.x + mv[5]*q1.y + mv[6]*q1.z + mv[7]*q1.w
                + mv[8]*q2.x + mv[9]*q2.y + mv[10]*q2.z + mv[11]*q2.w
                + mv[12]*q3.x + mv[13]*q3.y + mv[14]*q3.z + mv[15]*q3.w;
            cwacc += siluf(t) * cpk[1088 + hh];
        }
        cwf[n][hf][j] = cwacc;
    }
    __syncthreads();

    if (tid < 256) {   // coors reduce
        int n = tid >> 7, j = tid & 127;
        float cw = cwf[n][0][j] + cwf[n][1][j];
        float pnx = (n == 0) ? p0x : p1x;
        float pny = (n == 0) ? p0y : p1y;
        float pnz = (n == 0) ? p0z : p1z;
        float vx = cw * (pnx - px[j]), vy = cw * (pny - py[j]),
              vz = cw * (pnz - pz[j]);
        #pragma unroll
        for (int off = 32; off >= 1; off >>= 1) {
            vx += __shfl_xor(vx, off, 64);
            vy += __shfl_xor(vy, off, 64);
            vz += __shfl_xor(vz, off, 64);
        }
        if (lane == 0) { red[w][0] = vx; red[w][1] = vy; red[w][2] = vz; }
    }

    {   // node-MLP hidden
        int n = tid >> 8, h = tid & 255;
        size_t w1off = (size_t)layer * 144 * 256;
        float acc = loadf(b1r, layer * 256 + h, isbf);
        if (isbf) {
            const unsigned short* wp = (const unsigned short*)w1r + w1off + h;
            #pragma unroll 8
            for (int d = 0; d < 144; ++d) acc += ni[n][d] * b2f(wp[(size_t)d * 256]);
        } else {
            const float* wp = (const float*)w1r + w1off + h;
            #pragma unroll 8
            for (int d = 0; d < 144; ++d) acc += ni[n][d] * wp[(size_t)d * 256];
        }
        hid[n][h] = siluf(acc);
    }
    __syncthreads();

    if (tid < 6) {
        int n = tid / 3, c = tid - n * 3;
        int nd = node0 + n;
        coorsOut[nd * 3 + c] = coorsIn[nd * 3 + c]
            + red[n * 2][c] + red[n * 2 + 1][c];
    }
    {   // node-MLP out
        int n = tid >> 8, d = tid & 127, hf = (tid >> 7) & 1;
        size_t w2off = (size_t)layer * 256 * 128;
        float acc = hf ? 0.f : loadf(b2r, layer * 128 + d, isbf);
        if (isbf) {
            const unsigned short* wp = (const unsigned short*)w2r + w2off
                                     + (size_t)hf * 128 * 128 + d;
            #pragma unroll 8
            for (int h = 0; h < 128; ++h) acc += hid[n][hf * 128 + h] * b2f(wp[(size_t)h * 128]);
        } else {
            const float* wp = (const float*)w2r + w2off + (size_t)hf * 128 * 128 + d;
            #pragma unroll 8
            for (int h = 0; h < 128; ++h) acc += hid[n][hf * 128 + h] * wp[(size_t)h * 128];
        }
        part[n][hf][d] = acc;
    }
    __syncthreads();
    if (tid < 256) {
        int n = tid >> 7, d = tid & 127;
        float v = fr[n][d] + part[n][0][d] + part[n][1][d];
        feats[(size_t)(node0 + n) * DD + d] = v;
        fb16[(size_t)(node0 + n) * DD + d] = f2b(v);
    }
}

// ---------------- K4: mean pool ----------------
__global__ __launch_bounds__(128) void k4_pool(
    const float* __restrict__ feats, void* __restrict__ out,
    const int* __restrict__ flagp) {
    int b = blockIdx.x, d = threadIdx.x;
    float s = 0.f;
    for (int n = 0; n < NN; ++n) s += feats[((size_t)(b * NN + n)) * DD + d];
    float v = s * (1.0f / 128.0f);
    if (*flagp) ((unsigned short*)out)[b * DD + d] = f2b(v);
    else        ((float*)out)[b * DD + d] = v;
}

// ---------------- launch ----------------
extern "C" void kernel_launch(void* const* d_in, const int* in_sizes, int n_in,
                              void* d_out, int out_size, void* d_ws, size_t ws_size,
                              hipStream_t stream) {
    const int* z = (const int*)d_in[0];
    const void* pos  = d_in[1];
    const void* emb  = d_in[3];
    const void* e_w1 = d_in[4];
    const void* e_b1 = d_in[5];
    const void* e_w2 = d_in[6];
    const void* e_b2 = d_in[7];
    const void* c_w1 = d_in[8];
    const void* c_b1 = d_in[9];
    const void* c_w2 = d_in[10];
    const void* c_b2 = d_in[11];
    const void* ln_g = d_in[12];
    const void* ln_b = d_in[13];
    const void* n_w1 = d_in[14];
    const void* n_b1 = d_in[15];
    const void* n_w2 = d_in[16];
    const void* n_b2 = d_in[17];

    float* ws     = (float*)d_ws;
    float* feats  = ws + OFF_FEATS;
    float* coorsA = ws + OFF_COORSA;
    float* coorsB = ws + OFF_COORSB;
    float* Ab     = ws + OFF_AB;
    float* Bq     = ws + OFF_BQ;
    float* cpk    = ws + OFF_CPK;
    float* wlb    = ws + OFF_WLB;
    int4*  w2f    = (int4*)(ws + OFF_W2F);
    int*   flag   = (int*)(ws + OFF_FLAG);
    unsigned short* fb16 = (unsigned short*)(ws + OFF_FB16);
    int4*  w1f    = (int4*)(ws + OFF_W1F);

    k_init<<<856, 256, 0, stream>>>(
        z, pos, emb, e_w1, e_w2, e_b2, c_w1, c_b1, c_w2, c_b2,
        feats, fb16, coorsA, wlb, w2f, w1f, cpk, flag);

    float* cin = coorsA; float* cout = coorsB;
    for (int l = 0; l < DEPTH; ++l) {
        k1_ab<<<1088, 256, 0, stream>>>(
            fb16, w1f + (size_t)l * 68 * 4 * 64, e_b1,
            (unsigned int)(l * H1), Ab, Bq, flag);
        k2_pair<<<BATCH * NN / 2, 512, 0, stream>>>(
            Ab, Bq, cin, cout, feats, fb16,
            wlb + l * 560, (const short8*)(w2f + (size_t)l * NCH * 64),
            cpk + (size_t)l * 1216,
            ln_g, ln_b, n_w1, n_b1, n_w2, n_b2,
            (unsigned int)l, flag);
        float* t = cin; cin = cout; cout = t;
    }
    k4_pool<<<BATCH, 128, 0, stream>>>(feats, d_out, flag);
}